// Round 4
// baseline (36.812 us; speedup 1.0000x reference)
//
#include <hip/hip_runtime.h>
#include <hip/hip_bf16.h>

typedef short short8 __attribute__((ext_vector_type(8)));
typedef float f32x4 __attribute__((ext_vector_type(4)));

__device__ inline unsigned short f2bf(float f) {
    unsigned u = __builtin_bit_cast(unsigned, f);
    u += 0x7FFFu + ((u >> 16) & 1u);          // round-to-nearest-even
    return (unsigned short)(u >> 16);
}

// ---------------------------------------------------------------------------
// prep: Wm[d][c] = 0.25 * sum_h Wv[h*64+d][c], packed in MFMA B-fragment order:
//   Bf[((ct*8+kc)*64 + lane)*8 + j] = bf16(Wm[ct*16 + lane%16][kc*32 + (lane/16)*8 + j])
// bm[d] = 0.25 * sum_h bv[h*64+d]
// ---------------------------------------------------------------------------
__global__ __launch_bounds__(256)
void k_prep(const float* __restrict__ Wv, const float* __restrict__ bv,
            unsigned short* __restrict__ Bf, float* __restrict__ bm)
{
    const int t = blockIdx.x * 256 + threadIdx.x;   // 0..16383
    const int fi = t >> 9;                          // fragment index 0..31
    const int lane = (t >> 3) & 63;
    const int j = t & 7;
    const int ct = fi >> 3, kc = fi & 7;
    const int d = ct * 16 + (lane & 15);
    const int c = kc * 32 + (lane >> 4) * 8 + j;
    const float s = 0.25f * (Wv[(size_t)d * 256 + c] +
                             Wv[(size_t)(64 + d) * 256 + c] +
                             Wv[(size_t)(128 + d) * 256 + c] +
                             Wv[(size_t)(192 + d) * 256 + c]);
    Bf[t] = f2bf(s);
    if (t < 64)
        bm[t] = 0.25f * (bv[t] + bv[64 + t] + bv[128 + t] + bv[192 + t]);
}

// ---------------------------------------------------------------------------
// main: out[n][d] = sum_c source[n][c] * Wm[d][c] + bm[d]
// 256 threads = 4 waves; block owns 64 rows; wave w owns rows [blk*64+w*16,+16).
// Per wave (NO barriers, within-wave LDS only):
//   1. 16 fully-coalesced row loads: instr i = entire row (rowbase+i), lane
//      covers bytes lane*16.
//   2. f32->bf16 convert, ds_write_b64 into XOR-swizzled [16][512B] LDS tile
//      (byte ^= (row&7)<<4): write = contiguous permuted 512B (conflict-free),
//      read spreads 8 rows over all 8 16B-slots per 128B (2-way residual = free).
//   3. ds_read_b128 A-fragments; B fragments from global (L2-resident 32 KB).
// ---------------------------------------------------------------------------
__global__ __launch_bounds__(256, 4)
void k_vmean(const float* __restrict__ X, const unsigned short* __restrict__ Bf,
             const float* __restrict__ bm, float* __restrict__ out, int N)
{
    __shared__ unsigned char Xs[4][8192];           // 32 KB

    const int t = threadIdx.x;
    const int wave = t >> 6, lane = t & 63;
    const int rowbase = blockIdx.x * 64 + wave * 16;

    // 1. coalesced row loads: all 16 in flight
    float4 rb[16];
#pragma unroll
    for (int i = 0; i < 16; ++i) {
        int row = rowbase + i;
        if (row >= N) row = N - 1;                  // clamp tail (stores masked)
        rb[i] = *(const float4*)&X[(size_t)row * 256 + lane * 4];
    }

    // bias regs (L2-hot, tiny)
    const int col_lo = lane & 15;
    float bias[4];
#pragma unroll
    for (int ct = 0; ct < 4; ++ct) bias[ct] = bm[ct * 16 + col_lo];

    // 2. cvt + swizzled LDS write (row i, logical bytes 8*lane..+8)
    unsigned char* wbase = &Xs[wave][0];
#pragma unroll
    for (int i = 0; i < 16; ++i) {
        unsigned lo = (unsigned)f2bf(rb[i].x) | ((unsigned)f2bf(rb[i].y) << 16);
        unsigned hi = (unsigned)f2bf(rb[i].z) | ((unsigned)f2bf(rb[i].w) << 16);
        uint2 w; w.x = lo; w.y = hi;
        *(uint2*)(wbase + i * 512 + ((lane * 8) ^ ((i & 7) << 4))) = w;
    }

    // 3. MFMA: A from LDS (swizzled b128 reads), B from global/L2
    const int r = lane & 15, kgrp = lane >> 4;
    const unsigned char* rbase = wbase + r * 512;
    const int rx = (r & 7) << 4;
    f32x4 acc[4] = {};
#pragma unroll
    for (int kc = 0; kc < 8; ++kc) {
        const short8 a = *(const short8*)(rbase + ((kgrp * 16 + kc * 64) ^ rx));
#pragma unroll
        for (int ct = 0; ct < 4; ++ct) {
            const short8 b = *(const short8*)&Bf[((ct * 8 + kc) * 64 + lane) * 8];
            acc[ct] = __builtin_amdgcn_mfma_f32_16x16x32_bf16(a, b, acc[ct], 0, 0, 0);
        }
    }

    // epilogue: C/D layout col = lane&15, row = (lane>>4)*4 + reg  [m89-verified]
    const int orow0 = rowbase + kgrp * 4;
#pragma unroll
    for (int ct = 0; ct < 4; ++ct) {
        const int col = ct * 16 + col_lo;
#pragma unroll
        for (int rr = 0; rr < 4; ++rr) {
            const int row = orow0 + rr;
            if (row < N)
                out[(size_t)row * 64 + col] = acc[ct][rr] + bias[ct];
        }
    }
}

extern "C" void kernel_launch(void* const* d_in, const int* in_sizes, int n_in,
                              void* d_out, int out_size, void* d_ws, size_t ws_size,
                              hipStream_t stream)
{
    const float* sx = (const float*)d_in[1];        // source_input
    const float* Wv = (const float*)d_in[6];
    const float* bv = (const float*)d_in[7];
    float* out = (float*)d_out;

    unsigned short* Bf = (unsigned short*)d_ws;                 // 32 KB
    float* bm = (float*)((char*)d_ws + 16384 * sizeof(unsigned short));

    const int N = in_sizes[0] / 256;
    const int nblk = (N + 63) / 64;

    k_prep<<<64, 256, 0, stream>>>(Wv, bv, Bf, bm);
    k_vmean<<<nblk, 256, 0, stream>>>(sx, Bf, bm, out, N);
}